// Round 6
// baseline (117.037 us; speedup 1.0000x reference)
//
#include <hip/hip_runtime.h>

#define N_NODES 5000
#define N_EDGES 40000
#define ROWS 48            // BATCH * SEQ = 4*12
#define FIN 64
#define FOUT 64
#define NODE_ELEMS (ROWS * FIN)     // 3072
#define OUT_ROW 128                 // concat(FOUT, FOUT)
#define NODE_OUT (ROWS * OUT_ROW)   // 6144
#define CAP 64                      // per-node edge bucket capacity (max degree ~25)

typedef float f32x4 __attribute__((ext_vector_type(4)));

// ---------------- bucketed CSR ----------------

__global__ void zero_counts_kernel(int* __restrict__ counts) {
    int i = blockIdx.x * 256 + threadIdx.x;
    if (i < N_NODES) counts[i] = 0;
}

__global__ void bucket_kernel(const int* __restrict__ edges_dst,
                              const int* __restrict__ edges_src,
                              int* __restrict__ counts,
                              int* __restrict__ bucket) {
    int e = blockIdx.x * 256 + threadIdx.x;
    if (e < N_EDGES) {
        int d = edges_dst[e];
        int slot = atomicAdd(&counts[d], 1);
        if (slot < CAP) bucket[d * CAP + slot] = edges_src[e];
    }
}

// ---------------- Kernel 1: Q = bf16(F @ W) -> ws only ----------------

__global__ __launch_bounds__(256) void matmul_kernel(
    const float* __restrict__ feat,
    const float* __restrict__ W,
    unsigned short* __restrict__ Q) {
    __shared__ __align__(16) float lds[FIN * FOUT];  // 16 KB, staged W then features

    const int n = blockIdx.x;
    const int tid = threadIdx.x;
    const int j = tid & 63;

    // stage W
    {
        const f32x4* w4 = (const f32x4*)W;
        f32x4* l4 = (f32x4*)lds;
        #pragma unroll
        for (int i = 0; i < 4; ++i) l4[tid + i * 256] = w4[tid + i * 256];
    }
    __syncthreads();
    float wcol[64];
    #pragma unroll
    for (int k = 0; k < 64; ++k) wcol[k] = lds[k * 64 + j];
    __syncthreads();
    // stage this node's feature tile (reuse same LDS)
    {
        const f32x4* f4 = (const f32x4*)(feat + (size_t)n * NODE_ELEMS);
        f32x4* l4 = (f32x4*)lds;
        #pragma unroll
        for (int i = 0; i < 3; ++i) l4[tid + i * 256] = f4[tid + i * 256];
    }
    __syncthreads();

    unsigned short* qn = Q + (size_t)n * NODE_ELEMS;

    #pragma unroll
    for (int i = 0; i < 12; ++i) {
        int r = (tid + i * 256) >> 6;                    // uniform per wave
        const f32x4* m4 = (const f32x4*)(lds + r * 64);
        float s = 0.f;
        #pragma unroll
        for (int k4 = 0; k4 < 16; ++k4) {
            f32x4 m = m4[k4];
            s = fmaf(m.x, wcol[4 * k4 + 0], s);
            s = fmaf(m.y, wcol[4 * k4 + 1], s);
            s = fmaf(m.z, wcol[4 * k4 + 2], s);
            s = fmaf(m.w, wcol[4 * k4 + 3], s);
        }
        unsigned int u = __float_as_uint(s);             // f32 -> bf16 RNE
        u += 0x7fffu + ((u >> 16) & 1u);
        qn[r * FIN + j] = (unsigned short)(u >> 16);
    }
}

// ---------------- Kernel 2: out[n] = relu([Q[n], mean_src Q[src]]) ----------------

__device__ __forceinline__ void acc_u4(float* a, uint4 v) {
    a[0] += __uint_as_float(v.x << 16); a[1] += __uint_as_float(v.x & 0xffff0000u);
    a[2] += __uint_as_float(v.y << 16); a[3] += __uint_as_float(v.y & 0xffff0000u);
    a[4] += __uint_as_float(v.z << 16); a[5] += __uint_as_float(v.z & 0xffff0000u);
    a[6] += __uint_as_float(v.w << 16); a[7] += __uint_as_float(v.w & 0xffff0000u);
}
__device__ __forceinline__ void acc_u2(float* a, uint2 v) {
    a[0] += __uint_as_float(v.x << 16); a[1] += __uint_as_float(v.x & 0xffff0000u);
    a[2] += __uint_as_float(v.y << 16); a[3] += __uint_as_float(v.y & 0xffff0000u);
}

__global__ __launch_bounds__(256) void combine_kernel(
    const unsigned short* __restrict__ Q,
    const int* __restrict__ counts,
    const int* __restrict__ bucket,
    float* __restrict__ out) {
    __shared__ int s_src[CAP];
    const int n = blockIdx.x;
    const int tid = threadIdx.x;
    int cnt = counts[n];
    cnt = cnt < CAP ? cnt : CAP;

    if (tid < cnt) s_src[tid] = bucket[n * CAP + tid];
    __syncthreads();

    // own row -> left half
    float own[12];
    #pragma unroll
    for (int i = 0; i < 12; ++i) own[i] = 0.f;
    {
        const unsigned short* qn = Q + (size_t)n * NODE_ELEMS;
        uint4 oa = *(const uint4*)(qn + tid * 8);
        uint2 ob = *(const uint2*)(qn + 2048 + tid * 4);
        acc_u4(own, oa); acc_u2(own + 8, ob);
    }

    // neighbor mean -> right half
    float acc[12];
    #pragma unroll
    for (int i = 0; i < 12; ++i) acc[i] = 0.f;

    int e = 0;
    for (; e + 4 <= cnt; e += 4) {
        const unsigned short* q0 = Q + (size_t)s_src[e]     * NODE_ELEMS;
        const unsigned short* q1 = Q + (size_t)s_src[e + 1] * NODE_ELEMS;
        const unsigned short* q2 = Q + (size_t)s_src[e + 2] * NODE_ELEMS;
        const unsigned short* q3 = Q + (size_t)s_src[e + 3] * NODE_ELEMS;
        uint4 a0 = *(const uint4*)(q0 + tid * 8);
        uint4 a1 = *(const uint4*)(q1 + tid * 8);
        uint4 a2 = *(const uint4*)(q2 + tid * 8);
        uint4 a3 = *(const uint4*)(q3 + tid * 8);
        uint2 b0 = *(const uint2*)(q0 + 2048 + tid * 4);
        uint2 b1 = *(const uint2*)(q1 + 2048 + tid * 4);
        uint2 b2 = *(const uint2*)(q2 + 2048 + tid * 4);
        uint2 b3 = *(const uint2*)(q3 + 2048 + tid * 4);
        acc_u4(acc, a0); acc_u4(acc, a1); acc_u4(acc, a2); acc_u4(acc, a3);
        acc_u2(acc + 8, b0); acc_u2(acc + 8, b1);
        acc_u2(acc + 8, b2); acc_u2(acc + 8, b3);
    }
    for (; e < cnt; ++e) {
        const unsigned short* q0 = Q + (size_t)s_src[e] * NODE_ELEMS;
        uint4 a0 = *(const uint4*)(q0 + tid * 8);
        uint2 b0 = *(const uint2*)(q0 + 2048 + tid * 4);
        acc_u4(acc, a0); acc_u2(acc + 8, b0);
    }

    const float inv = 1.0f / (float)(cnt > 1 ? cnt : 1);
    float* outn = out + (size_t)n * NODE_OUT;

    // part A: elems 0..2047 -> row tid>>3, col (tid&7)*8
    {
        int r = tid >> 3, c = (tid & 7) * 8;
        float* pl = outn + r * OUT_ROW + c;        // left half
        float* pr = pl + 64;                       // right half
        f32x4 l0 = {fmaxf(own[0], 0.f), fmaxf(own[1], 0.f),
                    fmaxf(own[2], 0.f), fmaxf(own[3], 0.f)};
        f32x4 l1 = {fmaxf(own[4], 0.f), fmaxf(own[5], 0.f),
                    fmaxf(own[6], 0.f), fmaxf(own[7], 0.f)};
        f32x4 r0 = {fmaxf(acc[0] * inv, 0.f), fmaxf(acc[1] * inv, 0.f),
                    fmaxf(acc[2] * inv, 0.f), fmaxf(acc[3] * inv, 0.f)};
        f32x4 r1 = {fmaxf(acc[4] * inv, 0.f), fmaxf(acc[5] * inv, 0.f),
                    fmaxf(acc[6] * inv, 0.f), fmaxf(acc[7] * inv, 0.f)};
        *(f32x4*)(pl)     = l0;
        *(f32x4*)(pl + 4) = l1;
        *(f32x4*)(pr)     = r0;
        *(f32x4*)(pr + 4) = r1;
    }
    // part B: elems 2048..3071 -> row 32 + (tid>>4), col (tid&15)*4
    {
        int r = 32 + (tid >> 4), c = (tid & 15) * 4;
        float* pl = outn + r * OUT_ROW + c;
        float* pr = pl + 64;
        f32x4 l = {fmaxf(own[8], 0.f), fmaxf(own[9], 0.f),
                   fmaxf(own[10], 0.f), fmaxf(own[11], 0.f)};
        f32x4 rr = {fmaxf(acc[8] * inv, 0.f), fmaxf(acc[9] * inv, 0.f),
                    fmaxf(acc[10] * inv, 0.f), fmaxf(acc[11] * inv, 0.f)};
        *(f32x4*)(pl) = l;
        *(f32x4*)(pr) = rr;
    }
}

// ---------------- Fallback path (tiny ws) ----------------

__global__ void hist_kernel(const int* __restrict__ edges_dst, int* __restrict__ counts) {
    int e = blockIdx.x * 256 + threadIdx.x;
    if (e < N_EDGES) atomicAdd(&counts[edges_dst[e]], 1);
}

__global__ void scan_kernel(const int* __restrict__ counts,
                            int* __restrict__ offsets,
                            int* __restrict__ cursor) {
    __shared__ int buf[1024];
    __shared__ int carry_s;
    int tid = threadIdx.x;
    if (tid == 0) carry_s = 0;
    __syncthreads();
    for (int base = 0; base < N_NODES; base += 1024) {
        int i = base + tid;
        int v = (i < N_NODES) ? counts[i] : 0;
        buf[tid] = v;
        __syncthreads();
        int x = v;
        for (int off = 1; off < 1024; off <<= 1) {
            int t = (tid >= off) ? buf[tid - off] : 0;
            __syncthreads();
            x += t;
            buf[tid] = x;
            __syncthreads();
        }
        int c = carry_s;
        if (i < N_NODES) {
            int excl = c + x - v;
            offsets[i] = excl;
            cursor[i] = excl;
        }
        __syncthreads();
        if (tid == 0) carry_s = c + buf[1023];
        __syncthreads();
    }
    if (threadIdx.x == 0) offsets[N_NODES] = carry_s;
}

__global__ void scatter_kernel(const int* __restrict__ edges_dst,
                               const int* __restrict__ edges_src,
                               int* __restrict__ cursor,
                               int* __restrict__ csr_src) {
    int e = blockIdx.x * 256 + threadIdx.x;
    if (e < N_EDGES) {
        int d = edges_dst[e];
        int p = atomicAdd(&cursor[d], 1);
        csr_src[p] = edges_src[e];
    }
}

__global__ __launch_bounds__(256) void fused_kernel(
    const float* __restrict__ feat,
    const float* __restrict__ W,
    const int* __restrict__ offsets,
    const int* __restrict__ csr_src,
    float* __restrict__ out) {
    __shared__ __align__(16) float lds_w[FIN * FOUT];
    __shared__ __align__(16) float lds_t[NODE_ELEMS];

    const int n = blockIdx.x;
    const int tid = threadIdx.x;

    {
        const f32x4* w4 = (const f32x4*)W;
        f32x4* l4 = (f32x4*)lds_w;
        #pragma unroll
        for (int i = 0; i < 4; ++i) l4[tid + i * 256] = w4[tid + i * 256];
    }
    {
        const f32x4* f4 = (const f32x4*)(feat + (size_t)n * NODE_ELEMS);
        f32x4* l4 = (f32x4*)lds_t;
        #pragma unroll
        for (int i = 0; i < 3; ++i) l4[tid + i * 256] = f4[tid + i * 256];
    }
    __syncthreads();

    const int j = tid & 63;
    float wcol[64];
    #pragma unroll
    for (int k = 0; k < 64; ++k) wcol[k] = lds_w[k * 64 + j];

    float* outn = out + (size_t)n * NODE_OUT;

    #pragma unroll
    for (int i = 0; i < 12; ++i) {
        int r = (tid + i * 256) >> 6;
        const f32x4* m4 = (const f32x4*)(lds_t + r * 64);
        float s = 0.f;
        #pragma unroll
        for (int k4 = 0; k4 < 16; ++k4) {
            f32x4 m = m4[k4];
            s += m.x * wcol[4 * k4 + 0] + m.y * wcol[4 * k4 + 1] +
                 m.z * wcol[4 * k4 + 2] + m.w * wcol[4 * k4 + 3];
        }
        outn[r * OUT_ROW + j] = fmaxf(s, 0.f);
    }

    const int e0 = offsets[n], e1 = offsets[n + 1];
    f32x4 acc[3];
    #pragma unroll
    for (int i = 0; i < 3; ++i) acc[i] = (f32x4){0.f, 0.f, 0.f, 0.f};
    for (int e = e0; e < e1; ++e) {
        int src = csr_src[e];
        const f32x4* f4 = (const f32x4*)(feat + (size_t)src * NODE_ELEMS);
        #pragma unroll
        for (int i = 0; i < 3; ++i) acc[i] += f4[tid + i * 256];
    }
    const float inv = 1.0f / (float)((e1 - e0) > 1 ? (e1 - e0) : 1);

    __syncthreads();
    {
        f32x4* l4 = (f32x4*)lds_t;
        #pragma unroll
        for (int i = 0; i < 3; ++i) l4[tid + i * 256] = acc[i] * inv;
    }
    __syncthreads();

    #pragma unroll
    for (int i = 0; i < 12; ++i) {
        int r = (tid + i * 256) >> 6;
        const f32x4* m4 = (const f32x4*)(lds_t + r * 64);
        float s = 0.f;
        #pragma unroll
        for (int k4 = 0; k4 < 16; ++k4) {
            f32x4 m = m4[k4];
            s += m.x * wcol[4 * k4 + 0] + m.y * wcol[4 * k4 + 1] +
                 m.z * wcol[4 * k4 + 2] + m.w * wcol[4 * k4 + 3];
        }
        outn[r * OUT_ROW + 64 + j] = fmaxf(s, 0.f);
    }
}

// ---------------- launch ----------------

extern "C" void kernel_launch(void* const* d_in, const int* in_sizes, int n_in,
                              void* d_out, int out_size, void* d_ws, size_t ws_size,
                              hipStream_t stream) {
    const float* feat = (const float*)d_in[0];
    const float* W    = (const float*)d_in[1];
    const int* edst   = (const int*)d_in[2];
    const int* esrc   = (const int*)d_in[3];
    float* out = (float*)d_out;

    // bucket-path layout
    int* counts  = (int*)d_ws;                               // 5000 ints
    int* bucket  = (int*)((char*)d_ws + 20480);              // 5000*64 ints = 1.28 MB
    const size_t q_off = 20480 + (size_t)N_NODES * CAP * 4;  // 1,300,480 (256-aligned)
    unsigned short* Q = (unsigned short*)((char*)d_ws + q_off);
    const size_t q_bytes = (size_t)N_NODES * NODE_ELEMS * 2; // 30.72 MB

    if (ws_size >= q_off + q_bytes) {
        zero_counts_kernel<<<(N_NODES + 255) / 256, 256, 0, stream>>>(counts);
        bucket_kernel<<<(N_EDGES + 255) / 256, 256, 0, stream>>>(edst, esrc, counts, bucket);
        matmul_kernel<<<N_NODES, 256, 0, stream>>>(feat, W, Q);
        combine_kernel<<<N_NODES, 256, 0, stream>>>(Q, counts, bucket, out);
    } else {
        // fallback: packed CSR + fused f32 kernel (tiny ws)
        int* offsets = counts + N_NODES;
        int* cursor  = offsets + N_NODES + 1;
        int* csr_src = cursor + N_NODES;
        zero_counts_kernel<<<(N_NODES + 255) / 256, 256, 0, stream>>>(counts);
        hist_kernel<<<(N_EDGES + 255) / 256, 256, 0, stream>>>(edst, counts);
        scan_kernel<<<1, 1024, 0, stream>>>(counts, offsets, cursor);
        scatter_kernel<<<(N_EDGES + 255) / 256, 256, 0, stream>>>(edst, esrc, cursor, csr_src);
        fused_kernel<<<N_NODES, 256, 0, stream>>>(feat, W, offsets, csr_src, out);
    }
}

// Round 7
// 80.275 us; speedup vs baseline: 1.4580x; 1.4580x over previous
//
#include <hip/hip_runtime.h>

#define N_NODES 5000
#define N_EDGES 40000
#define ROWS 48            // BATCH * SEQ = 4*12
#define FIN 64
#define FOUT 64
#define NODE_ELEMS (ROWS * FIN)     // 3072
#define OUT_ROW 128                 // concat(FOUT, FOUT)
#define NODE_OUT (ROWS * OUT_ROW)   // 6144
#define CAP 64                      // per-node edge bucket capacity (max degree ~25)
#define M_ROWS (N_NODES * ROWS)     // 240000 global rows

typedef float f32x4 __attribute__((ext_vector_type(4)));
typedef short bf16x8 __attribute__((ext_vector_type(8)));

__device__ __forceinline__ unsigned short f32_to_bf16_rne(float f) {
    unsigned int u = __float_as_uint(f);
    u += 0x7fffu + ((u >> 16) & 1u);
    return (unsigned short)(u >> 16);
}

// ---------------- bucketed CSR ----------------

__global__ void zero_counts_kernel(int* __restrict__ counts) {
    int i = blockIdx.x * 256 + threadIdx.x;
    if (i < N_NODES) counts[i] = 0;
}

__global__ void bucket_kernel(const int* __restrict__ edges_dst,
                              const int* __restrict__ edges_src,
                              int* __restrict__ counts,
                              int* __restrict__ bucket) {
    int e = blockIdx.x * 256 + threadIdx.x;
    if (e < N_EDGES) {
        int d = edges_dst[e];
        int slot = atomicAdd(&counts[d], 1);
        if (slot < CAP) bucket[d * CAP + slot] = edges_src[e];
    }
}

// ---------------- Kernel 1: MFMA GEMM  left = relu(F@W), Q = bf16(F@W) ----------------
// [240000 x 64] x [64 x 64]. Block = 64 rows, 4 waves x (16 rows x 64 cols).

__global__ __launch_bounds__(256) void mfma_matmul_kernel(
    const float* __restrict__ feat,      // [M_ROWS][64]
    const float* __restrict__ W,         // [64][64]
    float* __restrict__ out,             // [M_ROWS][128] (left half written)
    unsigned short* __restrict__ Q) {    // [M_ROWS][64] bf16
    __shared__ __align__(16) unsigned short a_lds[64 * 64];  // 8 KB, XOR-swizzled 16B groups

    const int tid  = threadIdx.x;
    const int wave = tid >> 6;
    const int lane = tid & 63;
    const int row16 = lane & 15;   // A-row within 16-row tile; also C-col within 16
    const int koct  = lane >> 4;   // 0..3: which 8-wide k group

    const size_t g0 = (size_t)blockIdx.x * 64;

    // ---- stage A: 64 rows x 64 k, f32 -> bf16, swizzle: group' = kg ^ (r&7) ----
    {
        const f32x4* src = (const f32x4*)(feat + g0 * FIN);
        #pragma unroll
        for (int i = 0; i < 4; ++i) {
            int c = tid + i * 256;          // chunk of 4 floats
            f32x4 v = src[c];
            int r    = c >> 4;              // row 0..63
            int kg   = (c & 15) >> 1;       // 16B group 0..7
            int half = c & 1;
            unsigned short p0 = f32_to_bf16_rne(v.x);
            unsigned short p1 = f32_to_bf16_rne(v.y);
            unsigned short p2 = f32_to_bf16_rne(v.z);
            unsigned short p3 = f32_to_bf16_rne(v.w);
            int us = r * 64 + ((kg ^ (r & 7)) << 3) + half * 4;   // ushort index, 8B aligned
            ushort4 pk; pk.x = p0; pk.y = p1; pk.z = p2; pk.w = p3;
            *(ushort4*)(a_lds + us) = pk;
        }
    }

    // ---- B fragments from global W (L1/L2-resident, once per block) ----
    // frag[s][t]: lane holds B[k = s*32 + koct*8 + m][col = t*16 + row16], m=0..7
    bf16x8 bfrag[2][4];
    #pragma unroll
    for (int s = 0; s < 2; ++s) {
        #pragma unroll
        for (int t = 0; t < 4; ++t) {
            bf16x8 b;
            #pragma unroll
            for (int m = 0; m < 8; ++m) {
                int k = s * 32 + koct * 8 + m;
                b[m] = (short)f32_to_bf16_rne(W[k * 64 + t * 16 + row16]);
            }
            bfrag[s][t] = b;
        }
    }

    f32x4 acc[4];
    #pragma unroll
    for (int t = 0; t < 4; ++t) acc[t] = (f32x4){0.f, 0.f, 0.f, 0.f};

    __syncthreads();

    // ---- MFMA main: 2 k-steps x 4 n-tiles ----
    #pragma unroll
    for (int s = 0; s < 2; ++s) {
        int r  = wave * 16 + row16;
        int kg = s * 4 + koct;
        int us = r * 64 + ((kg ^ (r & 7)) << 3);      // 16B aligned
        bf16x8 a = *(const bf16x8*)(a_lds + us);
        #pragma unroll
        for (int t = 0; t < 4; ++t)
            acc[t] = __builtin_amdgcn_mfma_f32_16x16x32_bf16(a, bfrag[s][t], acc[t], 0, 0, 0);
    }

    // ---- epilogue: C/D layout col = lane&15, row = (lane>>4)*4 + reg ----
    #pragma unroll
    for (int t = 0; t < 4; ++t) {
        #pragma unroll
        for (int p = 0; p < 4; ++p) {
            size_t g = g0 + wave * 16 + koct * 4 + p;
            int col = t * 16 + row16;
            float v = acc[t][p];
            out[g * OUT_ROW + col] = fmaxf(v, 0.f);
            Q[g * FIN + col] = f32_to_bf16_rne(v);
        }
    }
}

// ---------------- Kernel 2: right half = relu(mean_src Q_bf16[src])  (R2-proven form) ----------------

__device__ __forceinline__ void acc_u4(float* a, uint4 v) {
    a[0] += __uint_as_float(v.x << 16); a[1] += __uint_as_float(v.x & 0xffff0000u);
    a[2] += __uint_as_float(v.y << 16); a[3] += __uint_as_float(v.y & 0xffff0000u);
    a[4] += __uint_as_float(v.z << 16); a[5] += __uint_as_float(v.z & 0xffff0000u);
    a[6] += __uint_as_float(v.w << 16); a[7] += __uint_as_float(v.w & 0xffff0000u);
}
__device__ __forceinline__ void acc_u2(float* a, uint2 v) {
    a[0] += __uint_as_float(v.x << 16); a[1] += __uint_as_float(v.x & 0xffff0000u);
    a[2] += __uint_as_float(v.y << 16); a[3] += __uint_as_float(v.y & 0xffff0000u);
}

__global__ __launch_bounds__(256) void gather_kernel(
    const unsigned short* __restrict__ Q,
    const int* __restrict__ counts,
    const int* __restrict__ bucket,
    float* __restrict__ out) {
    const int n = blockIdx.x;
    const int tid = threadIdx.x;
    const int cnt_true = counts[n];
    const int cnt = cnt_true < CAP ? cnt_true : CAP;
    const int* bk = bucket + n * CAP;

    float acc[12];
    #pragma unroll
    for (int i = 0; i < 12; ++i) acc[i] = 0.f;

    int e = 0;
    for (; e + 2 <= cnt; e += 2) {
        int s0 = bk[e];
        int s1 = bk[e + 1];
        const unsigned short* q0 = Q + (size_t)s0 * NODE_ELEMS;
        const unsigned short* q1 = Q + (size_t)s1 * NODE_ELEMS;
        uint4 a0 = *(const uint4*)(q0 + tid * 8);
        uint2 b0 = *(const uint2*)(q0 + 2048 + tid * 4);
        uint4 a1 = *(const uint4*)(q1 + tid * 8);
        uint2 b1 = *(const uint2*)(q1 + 2048 + tid * 4);
        acc_u4(acc, a0);  acc_u2(acc + 8, b0);
        acc_u4(acc, a1);  acc_u2(acc + 8, b1);
    }
    if (e < cnt) {
        int s0 = bk[e];
        const unsigned short* q0 = Q + (size_t)s0 * NODE_ELEMS;
        uint4 a0 = *(const uint4*)(q0 + tid * 8);
        uint2 b0 = *(const uint2*)(q0 + 2048 + tid * 4);
        acc_u4(acc, a0);  acc_u2(acc + 8, b0);
    }

    const float inv = 1.0f / (float)(cnt_true > 1 ? cnt_true : 1);
    float* outn = out + (size_t)n * NODE_OUT;

    // elems 0..2047: m = tid*8 -> row tid>>3, col (tid&7)*8
    {
        int r = tid >> 3, c = (tid & 7) * 8;
        float* p = outn + r * OUT_ROW + 64 + c;
        f32x4 v0 = {fmaxf(acc[0] * inv, 0.f), fmaxf(acc[1] * inv, 0.f),
                    fmaxf(acc[2] * inv, 0.f), fmaxf(acc[3] * inv, 0.f)};
        f32x4 v1 = {fmaxf(acc[4] * inv, 0.f), fmaxf(acc[5] * inv, 0.f),
                    fmaxf(acc[6] * inv, 0.f), fmaxf(acc[7] * inv, 0.f)};
        *(f32x4*)(p)     = v0;
        *(f32x4*)(p + 4) = v1;
    }
    // elems 2048..3071: m = 2048 + tid*4 -> row 32 + (tid>>4), col (tid&15)*4
    {
        int r = 32 + (tid >> 4), c = (tid & 15) * 4;
        float* p = outn + r * OUT_ROW + 64 + c;
        f32x4 v = {fmaxf(acc[8] * inv, 0.f), fmaxf(acc[9] * inv, 0.f),
                   fmaxf(acc[10] * inv, 0.f), fmaxf(acc[11] * inv, 0.f)};
        *(f32x4*)(p) = v;
    }
}

// ---------------- Fallback path (tiny ws): scan CSR + fused f32 kernel ----------------

__global__ void hist_kernel(const int* __restrict__ edges_dst, int* __restrict__ counts) {
    int e = blockIdx.x * 256 + threadIdx.x;
    if (e < N_EDGES) atomicAdd(&counts[edges_dst[e]], 1);
}

__global__ void scan_kernel(const int* __restrict__ counts,
                            int* __restrict__ offsets,
                            int* __restrict__ cursor) {
    __shared__ int buf[1024];
    __shared__ int carry_s;
    int tid = threadIdx.x;
    if (tid == 0) carry_s = 0;
    __syncthreads();
    for (int base = 0; base < N_NODES; base += 1024) {
        int i = base + tid;
        int v = (i < N_NODES) ? counts[i] : 0;
        buf[tid] = v;
        __syncthreads();
        int x = v;
        for (int off = 1; off < 1024; off <<= 1) {
            int t = (tid >= off) ? buf[tid - off] : 0;
            __syncthreads();
            x += t;
            buf[tid] = x;
            __syncthreads();
        }
        int c = carry_s;
        if (i < N_NODES) {
            int excl = c + x - v;
            offsets[i] = excl;
            cursor[i] = excl;
        }
        __syncthreads();
        if (tid == 0) carry_s = c + buf[1023];
        __syncthreads();
    }
    if (threadIdx.x == 0) offsets[N_NODES] = carry_s;
}

__global__ void scatter_kernel(const int* __restrict__ edges_dst,
                               const int* __restrict__ edges_src,
                               int* __restrict__ cursor,
                               int* __restrict__ csr_src) {
    int e = blockIdx.x * 256 + threadIdx.x;
    if (e < N_EDGES) {
        int d = edges_dst[e];
        int p = atomicAdd(&cursor[d], 1);
        csr_src[p] = edges_src[e];
    }
}

__global__ __launch_bounds__(256) void fused_kernel(
    const float* __restrict__ feat,
    const float* __restrict__ W,
    const int* __restrict__ offsets,
    const int* __restrict__ csr_src,
    float* __restrict__ out) {
    __shared__ __align__(16) float lds_w[FIN * FOUT];
    __shared__ __align__(16) float lds_t[NODE_ELEMS];

    const int n = blockIdx.x;
    const int tid = threadIdx.x;

    {
        const f32x4* w4 = (const f32x4*)W;
        f32x4* l4 = (f32x4*)lds_w;
        #pragma unroll
        for (int i = 0; i < 4; ++i) l4[tid + i * 256] = w4[tid + i * 256];
    }
    {
        const f32x4* f4 = (const f32x4*)(feat + (size_t)n * NODE_ELEMS);
        f32x4* l4 = (f32x4*)lds_t;
        #pragma unroll
        for (int i = 0; i < 3; ++i) l4[tid + i * 256] = f4[tid + i * 256];
    }
    __syncthreads();

    const int j = tid & 63;
    float wcol[64];
    #pragma unroll
    for (int k = 0; k < 64; ++k) wcol[k] = lds_w[k * 64 + j];

    float* outn = out + (size_t)n * NODE_OUT;

    #pragma unroll
    for (int i = 0; i < 12; ++i) {
        int r = (tid + i * 256) >> 6;
        const f32x4* m4 = (const f32x4*)(lds_t + r * 64);
        float s = 0.f;
        #pragma unroll
        for (int k4 = 0; k4 < 16; ++k4) {
            f32x4 m = m4[k4];
            s += m.x * wcol[4 * k4 + 0] + m.y * wcol[4 * k4 + 1] +
                 m.z * wcol[4 * k4 + 2] + m.w * wcol[4 * k4 + 3];
        }
        outn[r * OUT_ROW + j] = fmaxf(s, 0.f);
    }

    const int e0 = offsets[n], e1 = offsets[n + 1];
    f32x4 acc[3];
    #pragma unroll
    for (int i = 0; i < 3; ++i) acc[i] = (f32x4){0.f, 0.f, 0.f, 0.f};
    for (int e = e0; e < e1; ++e) {
        int src = csr_src[e];
        const f32x4* f4 = (const f32x4*)(feat + (size_t)src * NODE_ELEMS);
        #pragma unroll
        for (int i = 0; i < 3; ++i) acc[i] += f4[tid + i * 256];
    }
    const float inv = 1.0f / (float)((e1 - e0) > 1 ? (e1 - e0) : 1);

    __syncthreads();
    {
        f32x4* l4 = (f32x4*)lds_t;
        #pragma unroll
        for (int i = 0; i < 3; ++i) l4[tid + i * 256] = acc[i] * inv;
    }
    __syncthreads();

    #pragma unroll
    for (int i = 0; i < 12; ++i) {
        int r = (tid + i * 256) >> 6;
        const f32x4* m4 = (const f32x4*)(lds_t + r * 64);
        float s = 0.f;
        #pragma unroll
        for (int k4 = 0; k4 < 16; ++k4) {
            f32x4 m = m4[k4];
            s += m.x * wcol[4 * k4 + 0] + m.y * wcol[4 * k4 + 1] +
                 m.z * wcol[4 * k4 + 2] + m.w * wcol[4 * k4 + 3];
        }
        outn[r * OUT_ROW + 64 + j] = fmaxf(s, 0.f);
    }
}

// ---------------- launch ----------------

extern "C" void kernel_launch(void* const* d_in, const int* in_sizes, int n_in,
                              void* d_out, int out_size, void* d_ws, size_t ws_size,
                              hipStream_t stream) {
    const float* feat = (const float*)d_in[0];
    const float* W    = (const float*)d_in[1];
    const int* edst   = (const int*)d_in[2];
    const int* esrc   = (const int*)d_in[3];
    float* out = (float*)d_out;

    // bucket-path layout
    int* counts  = (int*)d_ws;                               // 5000 ints
    int* bucket  = (int*)((char*)d_ws + 20480);              // 5000*64 ints = 1.28 MB
    const size_t q_off = 20480 + (size_t)N_NODES * CAP * 4;  // 1,300,480 (256-aligned)
    unsigned short* Q = (unsigned short*)((char*)d_ws + q_off);
    const size_t q_bytes = (size_t)N_NODES * NODE_ELEMS * 2; // 30.72 MB

    if (ws_size >= q_off + q_bytes) {
        zero_counts_kernel<<<(N_NODES + 255) / 256, 256, 0, stream>>>(counts);
        bucket_kernel<<<(N_EDGES + 255) / 256, 256, 0, stream>>>(edst, esrc, counts, bucket);
        mfma_matmul_kernel<<<M_ROWS / 64, 256, 0, stream>>>(feat, W, out, Q);
        gather_kernel<<<N_NODES, 256, 0, stream>>>(Q, counts, bucket, out);
    } else {
        // fallback: packed CSR + fused f32 kernel (tiny ws)
        int* offsets = counts + N_NODES;
        int* cursor  = offsets + N_NODES + 1;
        int* csr_src = cursor + N_NODES;
        zero_counts_kernel<<<(N_NODES + 255) / 256, 256, 0, stream>>>(counts);
        hist_kernel<<<(N_EDGES + 255) / 256, 256, 0, stream>>>(edst, counts);
        scan_kernel<<<1, 1024, 0, stream>>>(counts, offsets, cursor);
        scatter_kernel<<<(N_EDGES + 255) / 256, 256, 0, stream>>>(edst, esrc, cursor, csr_src);
        fused_kernel<<<N_NODES, 256, 0, stream>>>(feat, W, offsets, csr_src, out);
    }
}

// Round 8
// 80.002 us; speedup vs baseline: 1.4629x; 1.0034x over previous
//
#include <hip/hip_runtime.h>

#define N_NODES 5000
#define N_EDGES 40000
#define ROWS 48            // BATCH * SEQ = 4*12
#define FIN 64
#define FOUT 64
#define NODE_ELEMS (ROWS * FIN)     // 3072
#define OUT_ROW 128                 // concat(FOUT, FOUT)
#define NODE_OUT (ROWS * OUT_ROW)   // 6144
#define CAP 64                      // per-node edge bucket capacity (max degree ~25)
#define M_ROWS (N_NODES * ROWS)     // 240000 global rows

typedef float f32x4 __attribute__((ext_vector_type(4)));
typedef short bf16x8 __attribute__((ext_vector_type(8)));

__device__ __forceinline__ unsigned short f32_to_bf16_rne(float f) {
    unsigned int u = __float_as_uint(f);
    u += 0x7fffu + ((u >> 16) & 1u);
    return (unsigned short)(u >> 16);
}

// ---------------- bucketed CSR ----------------

__global__ void zero_counts_kernel(int* __restrict__ counts) {
    int i = blockIdx.x * 256 + threadIdx.x;
    if (i < N_NODES) counts[i] = 0;
}

__global__ void bucket_kernel(const int* __restrict__ edges_dst,
                              const int* __restrict__ edges_src,
                              int* __restrict__ counts,
                              int* __restrict__ bucket) {
    int e = blockIdx.x * 256 + threadIdx.x;
    if (e < N_EDGES) {
        int d = edges_dst[e];
        int slot = atomicAdd(&counts[d], 1);
        if (slot < CAP) bucket[d * CAP + slot] = edges_src[e];
    }
}

// ---------------- Kernel 1: MFMA GEMM  left = relu(F@W), Q = bf16(F@W) ----------------
// [240000 x 64] x [64 x 64]. Block = 64 rows, 4 waves x (16 rows x 64 cols).

__global__ __launch_bounds__(256) void mfma_matmul_kernel(
    const float* __restrict__ feat,      // [M_ROWS][64]
    const float* __restrict__ W,         // [64][64]
    float* __restrict__ out,             // [M_ROWS][128] (left half written)
    unsigned short* __restrict__ Q) {    // [M_ROWS][64] bf16
    __shared__ __align__(16) unsigned short a_lds[64 * 64];  // 8 KB, XOR-swizzled 16B groups

    const int tid  = threadIdx.x;
    const int wave = tid >> 6;
    const int lane = tid & 63;
    const int row16 = lane & 15;   // A-row within 16-row tile; also C-col within 16
    const int koct  = lane >> 4;   // 0..3: which 8-wide k group

    const size_t g0 = (size_t)blockIdx.x * 64;

    // ---- stage A: 64 rows x 64 k, f32 -> bf16, swizzle: group' = kg ^ (r&7) ----
    {
        const f32x4* src = (const f32x4*)(feat + g0 * FIN);
        #pragma unroll
        for (int i = 0; i < 4; ++i) {
            int c = tid + i * 256;          // chunk of 4 floats
            f32x4 v = src[c];
            int r    = c >> 4;              // row 0..63
            int kg   = (c & 15) >> 1;       // 16B group 0..7
            int half = c & 1;
            unsigned short p0 = f32_to_bf16_rne(v.x);
            unsigned short p1 = f32_to_bf16_rne(v.y);
            unsigned short p2 = f32_to_bf16_rne(v.z);
            unsigned short p3 = f32_to_bf16_rne(v.w);
            int us = r * 64 + ((kg ^ (r & 7)) << 3) + half * 4;   // ushort index, 8B aligned
            ushort4 pk; pk.x = p0; pk.y = p1; pk.z = p2; pk.w = p3;
            *(ushort4*)(a_lds + us) = pk;
        }
    }

    // ---- B fragments from global W (L1/L2-resident, once per block) ----
    // frag[s][t]: lane holds B[k = s*32 + koct*8 + m][col = t*16 + row16], m=0..7
    bf16x8 bfrag[2][4];
    #pragma unroll
    for (int s = 0; s < 2; ++s) {
        #pragma unroll
        for (int t = 0; t < 4; ++t) {
            bf16x8 b;
            #pragma unroll
            for (int m = 0; m < 8; ++m) {
                int k = s * 32 + koct * 8 + m;
                b[m] = (short)f32_to_bf16_rne(W[k * 64 + t * 16 + row16]);
            }
            bfrag[s][t] = b;
        }
    }

    f32x4 acc[4];
    #pragma unroll
    for (int t = 0; t < 4; ++t) acc[t] = (f32x4){0.f, 0.f, 0.f, 0.f};

    __syncthreads();

    // ---- MFMA main: 2 k-steps x 4 n-tiles ----
    #pragma unroll
    for (int s = 0; s < 2; ++s) {
        int r  = wave * 16 + row16;
        int kg = s * 4 + koct;
        int us = r * 64 + ((kg ^ (r & 7)) << 3);      // 16B aligned
        bf16x8 a = *(const bf16x8*)(a_lds + us);
        #pragma unroll
        for (int t = 0; t < 4; ++t)
            acc[t] = __builtin_amdgcn_mfma_f32_16x16x32_bf16(a, bfrag[s][t], acc[t], 0, 0, 0);
    }

    // ---- epilogue: C/D layout col = lane&15, row = (lane>>4)*4 + reg ----
    #pragma unroll
    for (int t = 0; t < 4; ++t) {
        #pragma unroll
        for (int p = 0; p < 4; ++p) {
            size_t g = g0 + wave * 16 + koct * 4 + p;
            int col = t * 16 + row16;
            float v = acc[t][p];
            out[g * OUT_ROW + col] = fmaxf(v, 0.f);
            Q[g * FIN + col] = f32_to_bf16_rne(v);
        }
    }
}

// ---------------- Kernel 2: right half = relu(mean_src Q_bf16[src]) ----------------
// 384 threads x 8 elems = 3072; uint4-only loads; 4-deep edge ILP.

__device__ __forceinline__ void acc_u4(float* a, uint4 v) {
    a[0] += __uint_as_float(v.x << 16); a[1] += __uint_as_float(v.x & 0xffff0000u);
    a[2] += __uint_as_float(v.y << 16); a[3] += __uint_as_float(v.y & 0xffff0000u);
    a[4] += __uint_as_float(v.z << 16); a[5] += __uint_as_float(v.z & 0xffff0000u);
    a[6] += __uint_as_float(v.w << 16); a[7] += __uint_as_float(v.w & 0xffff0000u);
}

__global__ __launch_bounds__(384) void gather_kernel(
    const unsigned short* __restrict__ Q,
    const int* __restrict__ counts,
    const int* __restrict__ bucket,
    float* __restrict__ out) {
    const int n = blockIdx.x;
    const int tid = threadIdx.x;
    const int cnt_true = counts[n];
    const int cnt = cnt_true < CAP ? cnt_true : CAP;
    const int* bk = bucket + n * CAP;

    float acc[8];
    #pragma unroll
    for (int i = 0; i < 8; ++i) acc[i] = 0.f;

    int e = 0;
    for (; e + 4 <= cnt; e += 4) {
        const unsigned short* q0 = Q + (size_t)bk[e]     * NODE_ELEMS;
        const unsigned short* q1 = Q + (size_t)bk[e + 1] * NODE_ELEMS;
        const unsigned short* q2 = Q + (size_t)bk[e + 2] * NODE_ELEMS;
        const unsigned short* q3 = Q + (size_t)bk[e + 3] * NODE_ELEMS;
        uint4 a0 = *(const uint4*)(q0 + tid * 8);
        uint4 a1 = *(const uint4*)(q1 + tid * 8);
        uint4 a2 = *(const uint4*)(q2 + tid * 8);
        uint4 a3 = *(const uint4*)(q3 + tid * 8);
        acc_u4(acc, a0); acc_u4(acc, a1); acc_u4(acc, a2); acc_u4(acc, a3);
    }
    for (; e < cnt; ++e) {
        const unsigned short* q0 = Q + (size_t)bk[e] * NODE_ELEMS;
        uint4 a0 = *(const uint4*)(q0 + tid * 8);
        acc_u4(acc, a0);
    }

    const float inv = 1.0f / (float)(cnt_true > 1 ? cnt_true : 1);
    float* outn = out + (size_t)n * NODE_OUT;

    // m = tid*8 -> row tid>>3, col (tid&7)*8
    int r = tid >> 3, c = (tid & 7) * 8;
    float* p = outn + r * OUT_ROW + 64 + c;
    f32x4 v0 = {fmaxf(acc[0] * inv, 0.f), fmaxf(acc[1] * inv, 0.f),
                fmaxf(acc[2] * inv, 0.f), fmaxf(acc[3] * inv, 0.f)};
    f32x4 v1 = {fmaxf(acc[4] * inv, 0.f), fmaxf(acc[5] * inv, 0.f),
                fmaxf(acc[6] * inv, 0.f), fmaxf(acc[7] * inv, 0.f)};
    *(f32x4*)(p)     = v0;
    *(f32x4*)(p + 4) = v1;
}

// ---------------- Fallback path (tiny ws): scan CSR + fused f32 kernel ----------------

__global__ void hist_kernel(const int* __restrict__ edges_dst, int* __restrict__ counts) {
    int e = blockIdx.x * 256 + threadIdx.x;
    if (e < N_EDGES) atomicAdd(&counts[edges_dst[e]], 1);
}

__global__ void scan_kernel(const int* __restrict__ counts,
                            int* __restrict__ offsets,
                            int* __restrict__ cursor) {
    __shared__ int buf[1024];
    __shared__ int carry_s;
    int tid = threadIdx.x;
    if (tid == 0) carry_s = 0;
    __syncthreads();
    for (int base = 0; base < N_NODES; base += 1024) {
        int i = base + tid;
        int v = (i < N_NODES) ? counts[i] : 0;
        buf[tid] = v;
        __syncthreads();
        int x = v;
        for (int off = 1; off < 1024; off <<= 1) {
            int t = (tid >= off) ? buf[tid - off] : 0;
            __syncthreads();
            x += t;
            buf[tid] = x;
            __syncthreads();
        }
        int c = carry_s;
        if (i < N_NODES) {
            int excl = c + x - v;
            offsets[i] = excl;
            cursor[i] = excl;
        }
        __syncthreads();
        if (tid == 0) carry_s = c + buf[1023];
        __syncthreads();
    }
    if (threadIdx.x == 0) offsets[N_NODES] = carry_s;
}

__global__ void scatter_kernel(const int* __restrict__ edges_dst,
                               const int* __restrict__ edges_src,
                               int* __restrict__ cursor,
                               int* __restrict__ csr_src) {
    int e = blockIdx.x * 256 + threadIdx.x;
    if (e < N_EDGES) {
        int d = edges_dst[e];
        int p = atomicAdd(&cursor[d], 1);
        csr_src[p] = edges_src[e];
    }
}

__global__ __launch_bounds__(256) void fused_kernel(
    const float* __restrict__ feat,
    const float* __restrict__ W,
    const int* __restrict__ offsets,
    const int* __restrict__ csr_src,
    float* __restrict__ out) {
    __shared__ __align__(16) float lds_w[FIN * FOUT];
    __shared__ __align__(16) float lds_t[NODE_ELEMS];

    const int n = blockIdx.x;
    const int tid = threadIdx.x;

    {
        const f32x4* w4 = (const f32x4*)W;
        f32x4* l4 = (f32x4*)lds_w;
        #pragma unroll
        for (int i = 0; i < 4; ++i) l4[tid + i * 256] = w4[tid + i * 256];
    }
    {
        const f32x4* f4 = (const f32x4*)(feat + (size_t)n * NODE_ELEMS);
        f32x4* l4 = (f32x4*)lds_t;
        #pragma unroll
        for (int i = 0; i < 3; ++i) l4[tid + i * 256] = f4[tid + i * 256];
    }
    __syncthreads();

    const int j = tid & 63;
    float wcol[64];
    #pragma unroll
    for (int k = 0; k < 64; ++k) wcol[k] = lds_w[k * 64 + j];

    float* outn = out + (size_t)n * NODE_OUT;

    #pragma unroll
    for (int i = 0; i < 12; ++i) {
        int r = (tid + i * 256) >> 6;
        const f32x4* m4 = (const f32x4*)(lds_t + r * 64);
        float s = 0.f;
        #pragma unroll
        for (int k4 = 0; k4 < 16; ++k4) {
            f32x4 m = m4[k4];
            s += m.x * wcol[4 * k4 + 0] + m.y * wcol[4 * k4 + 1] +
                 m.z * wcol[4 * k4 + 2] + m.w * wcol[4 * k4 + 3];
        }
        outn[r * OUT_ROW + j] = fmaxf(s, 0.f);
    }

    const int e0 = offsets[n], e1 = offsets[n + 1];
    f32x4 acc[3];
    #pragma unroll
    for (int i = 0; i < 3; ++i) acc[i] = (f32x4){0.f, 0.f, 0.f, 0.f};
    for (int e = e0; e < e1; ++e) {
        int src = csr_src[e];
        const f32x4* f4 = (const f32x4*)(feat + (size_t)src * NODE_ELEMS);
        #pragma unroll
        for (int i = 0; i < 3; ++i) acc[i] += f4[tid + i * 256];
    }
    const float inv = 1.0f / (float)((e1 - e0) > 1 ? (e1 - e0) : 1);

    __syncthreads();
    {
        f32x4* l4 = (f32x4*)lds_t;
        #pragma unroll
        for (int i = 0; i < 3; ++i) l4[tid + i * 256] = acc[i] * inv;
    }
    __syncthreads();

    #pragma unroll
    for (int i = 0; i < 12; ++i) {
        int r = (tid + i * 256) >> 6;
        const f32x4* m4 = (const f32x4*)(lds_t + r * 64);
        float s = 0.f;
        #pragma unroll
        for (int k4 = 0; k4 < 16; ++k4) {
            f32x4 m = m4[k4];
            s += m.x * wcol[4 * k4 + 0] + m.y * wcol[4 * k4 + 1] +
                 m.z * wcol[4 * k4 + 2] + m.w * wcol[4 * k4 + 3];
        }
        outn[r * OUT_ROW + 64 + j] = fmaxf(s, 0.f);
    }
}

// ---------------- launch ----------------

extern "C" void kernel_launch(void* const* d_in, const int* in_sizes, int n_in,
                              void* d_out, int out_size, void* d_ws, size_t ws_size,
                              hipStream_t stream) {
    const float* feat = (const float*)d_in[0];
    const float* W    = (const float*)d_in[1];
    const int* edst   = (const int*)d_in[2];
    const int* esrc   = (const int*)d_in[3];
    float* out = (float*)d_out;

    // bucket-path layout
    int* counts  = (int*)d_ws;                               // 5000 ints
    int* bucket  = (int*)((char*)d_ws + 20480);              // 5000*64 ints = 1.28 MB
    const size_t q_off = 20480 + (size_t)N_NODES * CAP * 4;  // 1,300,480 (256-aligned)
    unsigned short* Q = (unsigned short*)((char*)d_ws + q_off);
    const size_t q_bytes = (size_t)N_NODES * NODE_ELEMS * 2; // 30.72 MB

    if (ws_size >= q_off + q_bytes) {
        zero_counts_kernel<<<(N_NODES + 255) / 256, 256, 0, stream>>>(counts);
        bucket_kernel<<<(N_EDGES + 255) / 256, 256, 0, stream>>>(edst, esrc, counts, bucket);
        mfma_matmul_kernel<<<M_ROWS / 64, 256, 0, stream>>>(feat, W, out, Q);
        gather_kernel<<<N_NODES, 384, 0, stream>>>(Q, counts, bucket, out);
    } else {
        // fallback: packed CSR + fused f32 kernel (tiny ws)
        int* offsets = counts + N_NODES;
        int* cursor  = offsets + N_NODES + 1;
        int* csr_src = cursor + N_NODES;
        zero_counts_kernel<<<(N_NODES + 255) / 256, 256, 0, stream>>>(counts);
        hist_kernel<<<(N_EDGES + 255) / 256, 256, 0, stream>>>(edst, counts);
        scan_kernel<<<1, 1024, 0, stream>>>(counts, offsets, cursor);
        scatter_kernel<<<(N_EDGES + 255) / 256, 256, 0, stream>>>(edst, esrc, cursor, csr_src);
        fused_kernel<<<N_NODES, 256, 0, stream>>>(feat, W, offsets, csr_src, out);
    }
}